// Round 6
// baseline (772.799 us; speedup 1.0000x reference)
//
#include <hip/hip_runtime.h>

typedef __attribute__((ext_vector_type(8))) short bf16x8;
typedef __attribute__((ext_vector_type(4))) float f32x4;
typedef __attribute__((ext_vector_type(4))) unsigned short us4;

typedef __attribute__((address_space(3))) void lds_void_t;
typedef const __attribute__((address_space(1))) void gbl_void_t;

__device__ __forceinline__ float bf2f(unsigned short u) {
    union { unsigned int i; float f; } x; x.i = ((unsigned int)u) << 16; return x.f;
}
__device__ __forceinline__ unsigned short f2bf(float f) {
    union { float f; unsigned int i; } x; x.f = f;
    unsigned int u = x.i;
    unsigned int r = (u + 0x7FFFu + ((u >> 16) & 1u)) >> 16;  // RNE
    return (unsigned short)r;
}

// ---------------------------------------------------------------------------
// f32 -> bf16 convert, 4 elems/thread, grid-stride.
// ---------------------------------------------------------------------------
__global__ __launch_bounds__(256) void conv_f32_bf16(
    const float* __restrict__ src, unsigned short* __restrict__ dst, long n4)
{
    long i = (long)blockIdx.x * blockDim.x + threadIdx.x;
    const long stride = (long)gridDim.x * blockDim.x;
    const float4* s = (const float4*)src;
    for (; i < n4; i += stride) {
        float4 v = s[i];
        us4 o = { f2bf(v.x), f2bf(v.y), f2bf(v.z), f2bf(v.w) };
        *(us4*)&dst[i * 4] = o;
    }
}

// ---------------------------------------------------------------------------
// Transpose: W(K x N) f32 -> Wt(N x K) bf16. 64x64 LDS tiles.
// ---------------------------------------------------------------------------
__global__ __launch_bounds__(256) void transpose_f32_bf16(
    const float* __restrict__ W, unsigned short* __restrict__ Wt, int K, int N)
{
    __shared__ unsigned short t[64][65];
    const int n0 = blockIdx.x * 64, k0 = blockIdx.y * 64;
    const int tid = threadIdx.x;
#pragma unroll
    for (int i = 0; i < 16; i++) {
        const int idx = tid + i * 256;
        const int r = idx >> 6, c = idx & 63;
        t[c][r] = f2bf(W[(long)(k0 + r) * N + (n0 + c)]);
    }
    __syncthreads();
#pragma unroll
    for (int i = 0; i < 16; i++) {
        const int idx = tid + i * 256;
        const int r = idx >> 6, c = idx & 63;
        Wt[(long)(n0 + r) * K + (k0 + c)] = t[r][c];
    }
}

// ---------------------------------------------------------------------------
// bf16 GEMM:  C[m][n] = sum_k A[m][k] * Bt[n][k]   (Bt = B^T layout)
// Tile 128x128, BK=32, 256 threads (4 waves, 64x64 each), mfma_f32_16x16x32_bf16.
// Staging: global_load_lds width=16, SINGLE-buffered [128][32] LDS.
// (Round-5 post-mortem: explicit double-buffer regressed scores 76->98us —
//  LDS 32KB halved blocks/CU; TLP > intra-wave pipelining here. m99-consistent.)
// XOR swizzle on the global k-chunk so MFMA-side ds_read_b128 is 2-way (free).
// SM: 0 bf16 row-major | 1 bf16 VhT head-split-transposed | 2 f32 row-major
//     3 scores-fused: P=exp(s*it) w/ mask, rowsum->atomicAdd L
//     4 PV: bf16 row-major scaled by 1/L[row]
// ---------------------------------------------------------------------------
template <int SM>
__global__ __launch_bounds__(256) void gemm_bt(
    const unsigned short* __restrict__ A,
    const unsigned short* __restrict__ Bt,
    void* __restrict__ C,
    int K, int lda, int ldb, int ldc,
    long Ah, long Ab, long Bh, long Bb, long Ch, long Cb,
    int bg,
    const unsigned char* __restrict__ mask, float* __restrict__ L,
    float inv_temp, int b0)
{
    const int tid  = threadIdx.x;
    const int wave = tid >> 6;
    const int lane = tid & 63;
    const int quad = lane >> 4;
    const int l16  = lane & 15;

    const int z  = blockIdx.z;
    const int h  = z / bg;
    const int bi = z - h * bg;
    A  += h * Ah + (long)bi * Ab;
    Bt += h * Bh + (long)bi * Bb;

    const int m0 = blockIdx.y * 128;
    const int n0 = blockIdx.x * 128;

    __shared__ __align__(16) unsigned short As[128 * 32];
    __shared__ __align__(16) unsigned short Bs[128 * 32];

    f32x4 acc[4][4];
#pragma unroll
    for (int i = 0; i < 4; i++)
#pragma unroll
        for (int j = 0; j < 4; j++) acc[i][j] = (f32x4){0.f, 0.f, 0.f, 0.f};

    const int wr = (wave >> 1) * 64;
    const int wc = (wave & 1) * 64;

    // staging: pass p covers linear 16B-chunks idx = p*256 + tid
    // row = idx>>2, slot = idx&3, global kc = slot ^ ((row>>2)&3)
    const int r0 = tid >> 2;
    const int kc = (tid & 3) ^ ((r0 >> 2) & 3);

    const unsigned short* A0 = A + (long)(m0 + r0) * lda + kc * 8;
    const unsigned short* A1 = A + (long)(m0 + r0 + 64) * lda + kc * 8;
    const unsigned short* B0 = Bt + (long)(n0 + r0) * ldb + kc * 8;
    const unsigned short* B1 = Bt + (long)(n0 + r0 + 64) * ldb + kc * 8;

    // wave-uniform LDS bases (lane lands at base + lane*16B)
    unsigned short* lAs0 = &As[(wave * 64) * 8];
    unsigned short* lAs1 = &As[(256 + wave * 64) * 8];
    unsigned short* lBs0 = &Bs[(wave * 64) * 8];
    unsigned short* lBs1 = &Bs[(256 + wave * 64) * 8];

    const int sw = (l16 >> 2) & 3;  // read-side XOR swizzle

    for (int kt = 0; kt < K; kt += 32) {
        __builtin_amdgcn_global_load_lds((gbl_void_t*)(A0 + kt), (lds_void_t*)lAs0, 16, 0, 0);
        __builtin_amdgcn_global_load_lds((gbl_void_t*)(A1 + kt), (lds_void_t*)lAs1, 16, 0, 0);
        __builtin_amdgcn_global_load_lds((gbl_void_t*)(B0 + kt), (lds_void_t*)lBs0, 16, 0, 0);
        __builtin_amdgcn_global_load_lds((gbl_void_t*)(B1 + kt), (lds_void_t*)lBs1, 16, 0, 0);
        __syncthreads();

        bf16x8 af[4], bf[4];
#pragma unroll
        for (int mi = 0; mi < 4; mi++)
            af[mi] = *(const bf16x8*)&As[(wr + mi * 16 + l16) * 32 + ((quad ^ sw) << 3)];
#pragma unroll
        for (int ni = 0; ni < 4; ni++)
            bf[ni] = *(const bf16x8*)&Bs[(wc + ni * 16 + l16) * 32 + ((quad ^ sw) << 3)];

#pragma unroll
        for (int mi = 0; mi < 4; mi++)
#pragma unroll
            for (int ni = 0; ni < 4; ni++)
                acc[mi][ni] = __builtin_amdgcn_mfma_f32_16x16x32_bf16(
                    af[mi], bf[ni], acc[mi][ni], 0, 0, 0);
        __syncthreads();
    }

    const long coff = h * Ch + (long)bi * Cb;
    if (SM == 0) {
        unsigned short* Cp = (unsigned short*)C + coff;
#pragma unroll
        for (int mi = 0; mi < 4; mi++)
#pragma unroll
            for (int ni = 0; ni < 4; ni++) {
                const int col = n0 + wc + ni * 16 + l16;
#pragma unroll
                for (int r = 0; r < 4; r++) {
                    const int row = m0 + wr + mi * 16 + quad * 4 + r;
                    Cp[(long)row * ldc + col] = f2bf(acc[mi][ni][r]);
                }
            }
    } else if (SM == 1) {
        // VhT store: col -> (h2=col>>9, d=col&511), row -> (bi2=row>>10, s=row&1023)
        unsigned short* Cp = (unsigned short*)C;
#pragma unroll
        for (int mi = 0; mi < 4; mi++)
#pragma unroll
            for (int ni = 0; ni < 4; ni++) {
                const int col = n0 + wc + ni * 16 + l16;
                const int h2 = col >> 9, d = col & 511;
                const int rowb = m0 + wr + mi * 16 + quad * 4;
                const int bi2 = rowb >> 10, s = rowb & 1023;
                us4 val = { f2bf(acc[mi][ni][0]), f2bf(acc[mi][ni][1]),
                            f2bf(acc[mi][ni][2]), f2bf(acc[mi][ni][3]) };
                *(us4*)&Cp[(((long)(h2 * bg + bi2) * 512 + d) << 10) + s] = val;
            }
    } else if (SM == 2) {
        float* Cp = (float*)C + coff;
#pragma unroll
        for (int mi = 0; mi < 4; mi++)
#pragma unroll
            for (int ni = 0; ni < 4; ni++) {
                const int col = n0 + wc + ni * 16 + l16;
#pragma unroll
                for (int r = 0; r < 4; r++) {
                    const int row = m0 + wr + mi * 16 + quad * 4 + r;
                    Cp[(long)row * ldc + col] = acc[mi][ni][r];
                }
            }
    } else if (SM == 3) {
        // fused scores epilogue: p = mask ? 0 : exp(s*inv_temp); store bf16;
        // row-sums -> atomicAdd into L[z*1024 + row] (16-lane shuffle reduce).
        unsigned short* Cp = (unsigned short*)C + coff;
        const unsigned char* mb = mask + ((long)(b0 + bi) << 20);
        float* Lz = L + ((long)z << 10);
#pragma unroll
        for (int mi = 0; mi < 4; mi++) {
#pragma unroll
            for (int r = 0; r < 4; r++) {
                const int row = m0 + wr + mi * 16 + quad * 4 + r;
                float rs = 0.f;
#pragma unroll
                for (int ni = 0; ni < 4; ni++) {
                    const int col = n0 + wc + ni * 16 + l16;
                    float p = __expf(acc[mi][ni][r] * inv_temp);
                    if (mb[((long)row << 10) + col] != 0) p = 0.f;
                    Cp[(long)row * ldc + col] = f2bf(p);
                    rs += p;
                }
#pragma unroll
                for (int m = 1; m < 16; m <<= 1) rs += __shfl_xor(rs, m);
                if (l16 == 0) atomicAdd(&Lz[row], rs);
            }
        }
    } else {
        // PV epilogue: scale by 1/L[row], bf16 row-major store.
        unsigned short* Cp = (unsigned short*)C + coff;
        const float* Lz = L + ((long)z << 10);
#pragma unroll
        for (int mi = 0; mi < 4; mi++)
#pragma unroll
            for (int r = 0; r < 4; r++) {
                const int row = m0 + wr + mi * 16 + quad * 4 + r;
                const float inv = 1.0f / Lz[row];
#pragma unroll
                for (int ni = 0; ni < 4; ni++) {
                    const int col = n0 + wc + ni * 16 + l16;
                    Cp[(long)row * ldc + col] = f2bf(acc[mi][ni][r] * inv);
                }
            }
    }
}

// ---------------------------------------------------------------------------
// Fused: sum 4 split-K partials (f32, rows of 512) + LayerNorm -> f32 out.
// ---------------------------------------------------------------------------
__global__ __launch_bounds__(256) void ln_rows_red4(
    const float* __restrict__ Yp, long zs,
    const float* __restrict__ gamma,
    const float* __restrict__ beta,
    float* __restrict__ out)
{
    __shared__ float red[4];
    const long row = blockIdx.x;
    const float* y = Yp + (row << 9);
    const int tid = threadIdx.x;
    const int wave = tid >> 6, lane = tid & 63;

    float v0 = y[tid] + y[zs + tid] + y[2 * zs + tid] + y[3 * zs + tid];
    float v1 = y[tid + 256] + y[zs + tid + 256] + y[2 * zs + tid + 256] + y[3 * zs + tid + 256];
    float sm = v0 + v1;
#pragma unroll
    for (int i = 32; i > 0; i >>= 1) sm += __shfl_xor(sm, i);
    if (lane == 0) red[wave] = sm;
    __syncthreads();
    sm = red[0] + red[1] + red[2] + red[3];
    __syncthreads();
    const float mu = sm * (1.0f / 512.0f);

    const float d0 = v0 - mu, d1 = v1 - mu;
    float sq = d0 * d0 + d1 * d1;
#pragma unroll
    for (int i = 32; i > 0; i >>= 1) sq += __shfl_xor(sq, i);
    if (lane == 0) red[wave] = sq;
    __syncthreads();
    sq = red[0] + red[1] + red[2] + red[3];
    const float inv = rsqrtf(sq * (1.0f / 512.0f) + 1e-5f);

    out[(row << 9) + tid]       = d0 * inv * gamma[tid]       + beta[tid];
    out[(row << 9) + tid + 256] = d1 * inv * gamma[tid + 256] + beta[tid + 256];
}

// ---------------------------------------------------------------------------
extern "C" void kernel_launch(void* const* d_in, const int* in_sizes, int n_in,
                              void* d_out, int out_size, void* d_ws, size_t ws_size,
                              hipStream_t stream)
{
    const float* q_f  = (const float*)d_in[0];
    const float* k_f  = (const float*)d_in[1];
    const float* v_f  = (const float*)d_in[2];
    const float* Wq_f = (const float*)d_in[3];
    const float* Wk_f = (const float*)d_in[4];
    const float* Wv_f = (const float*)d_in[5];
    const float* Wo_f = (const float*)d_in[6];
    const float* ga_f = (const float*)d_in[7];
    const float* be_f = (const float*)d_in[8];
    const unsigned char* mask = (const unsigned char*)d_in[9];
    float* out = (float*)d_out;

    constexpr int B = 8, S = 1024, DM = 512, H = 8, DH = 512, HD = H * DH;  // HD=4096
    const float inv_temp = 0.044194173824159216f;  // 1/sqrt(512)

    size_t off = 0;
    auto alloc = [&](size_t bytes) {
        void* p = (char*)d_ws + off;
        off += (bytes + 255) & ~(size_t)255;
        return p;
    };
    unsigned short* qb  = (unsigned short*)alloc((size_t)B * S * DM * 2);
    unsigned short* kb  = (unsigned short*)alloc((size_t)B * S * DM * 2);
    unsigned short* vb  = (unsigned short*)alloc((size_t)B * S * DM * 2);
    unsigned short* WqT = (unsigned short*)alloc((size_t)HD * DM * 2);
    unsigned short* WkT = (unsigned short*)alloc((size_t)HD * DM * 2);
    unsigned short* WvT = (unsigned short*)alloc((size_t)HD * DM * 2);
    unsigned short* WoT = (unsigned short*)alloc((size_t)DH * HD * 2);
    const size_t fixed = off;

    // Ypart (4 split-K f32 partials) aliases P (dead after PV).
    const size_t perbatch = (size_t)4 * S * HD * 2   // Qh,Kh,VhT,AO
                          + (size_t)H * S * S * 2    // P / Ypart
                          + (size_t)H * S * 4        // L
                          + 8 * 256;
    int bg = 8;
    while (bg > 1 && fixed + perbatch * (size_t)bg > ws_size) bg >>= 1;

    unsigned short* Qh  = (unsigned short*)alloc((size_t)bg * S * HD * 2);
    unsigned short* Kh  = (unsigned short*)alloc((size_t)bg * S * HD * 2);
    unsigned short* VhT = (unsigned short*)alloc((size_t)bg * S * HD * 2);
    unsigned short* AO  = (unsigned short*)alloc((size_t)bg * S * HD * 2);
    float* L = (float*)alloc((size_t)H * bg * S * 4);
    void* PY = alloc((size_t)H * bg * S * S * 2);  // >= 4*bg*S*DH*4
    unsigned short* P = (unsigned short*)PY;
    float* Ypart = (float*)PY;

    // ---- canonicalization: f32 -> bf16 (+ weight transposes) ----
    const long nqkv4 = (long)B * S * DM / 4;
    conv_f32_bf16<<<2048, 256, 0, stream>>>(q_f, qb, nqkv4);
    conv_f32_bf16<<<2048, 256, 0, stream>>>(k_f, kb, nqkv4);
    conv_f32_bf16<<<2048, 256, 0, stream>>>(v_f, vb, nqkv4);
    transpose_f32_bf16<<<dim3(HD / 64, DM / 64), 256, 0, stream>>>(Wq_f, WqT, DM, HD);
    transpose_f32_bf16<<<dim3(HD / 64, DM / 64), 256, 0, stream>>>(Wk_f, WkT, DM, HD);
    transpose_f32_bf16<<<dim3(HD / 64, DM / 64), 256, 0, stream>>>(Wv_f, WvT, DM, HD);
    transpose_f32_bf16<<<dim3(DH / 64, HD / 64), 256, 0, stream>>>(Wo_f, WoT, HD, DH);

    for (int g = 0; g < B / bg; g++) {
        const long inoff = (long)g * bg * S * DM;
        const int  Mg = bg * S;

        // ---- QKV projections: (Mg x 512) x (512 x 4096) ----
        gemm_bt<0><<<dim3(HD / 128, Mg / 128, 1), 256, 0, stream>>>(
            qb + inoff, WqT, Qh, DM, DM, DM, HD, 0, 0, 0, 0, 0, 0, bg,
            nullptr, nullptr, 0.f, 0);
        gemm_bt<0><<<dim3(HD / 128, Mg / 128, 1), 256, 0, stream>>>(
            kb + inoff, WkT, Kh, DM, DM, DM, HD, 0, 0, 0, 0, 0, 0, bg,
            nullptr, nullptr, 0.f, 0);
        gemm_bt<1><<<dim3(HD / 128, Mg / 128, 1), 256, 0, stream>>>(
            vb + inoff, WvT, VhT, DM, DM, DM, HD, 0, 0, 0, 0, 0, 0, bg,
            nullptr, nullptr, 0.f, 0);

        // ---- zero the row-sum accumulator ----
        hipMemsetAsync(L, 0, (size_t)H * bg * S * 4, stream);

        // ---- fused scores+exp+mask (+rowsum): P = exp(QK^T*it), L = rowsums ----
        gemm_bt<3><<<dim3(S / 128, S / 128, H * bg), 256, 0, stream>>>(
            Qh, Kh, P, DH, HD, HD, S,
            (long)DH, (long)S * HD,
            (long)DH, (long)S * HD,
            (long)bg * S * S, (long)S * S,
            bg, mask, L, inv_temp, g * bg);

        // ---- PV with 1/L normalization: AO = (P/L) * V ----
        gemm_bt<4><<<dim3(DH / 128, S / 128, H * bg), 256, 0, stream>>>(
            P, VhT, AO, S, S, S, HD,
            (long)bg * S * S, (long)S * S,
            (long)bg * DH * S, (long)DH * S,
            (long)DH, (long)S * HD,
            bg, nullptr, L, 0.f, 0);

        // ---- O-projection, split-K x4 -> Ypart ----
        gemm_bt<2><<<dim3(DH / 128, Mg / 128, 4), 256, 0, stream>>>(
            AO, WoT, Ypart, HD / 4, HD, HD, DH,
            1024, 0, 1024, 0, (long)Mg * DH, 0, 1,
            nullptr, nullptr, 0.f, 0);

        // ---- reduce partials + LayerNorm -> f32 out ----
        ln_rows_red4<<<dim3(Mg), 256, 0, stream>>>(
            Ypart, (long)Mg * DH, ga_f, be_f, out + (long)g * bg * S * DH);
    }
}

// Round 8
// 730.017 us; speedup vs baseline: 1.0586x; 1.0586x over previous
//
#include <hip/hip_runtime.h>

typedef __attribute__((ext_vector_type(8))) short bf16x8;
typedef __attribute__((ext_vector_type(4))) float f32x4;
typedef __attribute__((ext_vector_type(4))) unsigned short us4;

typedef __attribute__((address_space(3))) void lds_void_t;
typedef const __attribute__((address_space(1))) void gbl_void_t;

__device__ __forceinline__ float bf2f(unsigned short u) {
    union { unsigned int i; float f; } x; x.i = ((unsigned int)u) << 16; return x.f;
}
__device__ __forceinline__ unsigned short f2bf(float f) {
    union { float f; unsigned int i; } x; x.f = f;
    unsigned int u = x.i;
    unsigned int r = (u + 0x7FFFu + ((u >> 16) & 1u)) >> 16;  // RNE
    return (unsigned short)r;
}

// ---------------------------------------------------------------------------
// f32 -> bf16 convert, 4 elems/thread, grid-stride.
// ---------------------------------------------------------------------------
__global__ __launch_bounds__(256) void conv_f32_bf16(
    const float* __restrict__ src, unsigned short* __restrict__ dst, long n4)
{
    long i = (long)blockIdx.x * blockDim.x + threadIdx.x;
    const long stride = (long)gridDim.x * blockDim.x;
    const float4* s = (const float4*)src;
    for (; i < n4; i += stride) {
        float4 v = s[i];
        us4 o = { f2bf(v.x), f2bf(v.y), f2bf(v.z), f2bf(v.w) };
        *(us4*)&dst[i * 4] = o;
    }
}

// ---------------------------------------------------------------------------
// Transpose: W(K x N) f32 -> Wt(N x K) bf16. 64x64 LDS tiles.
// ---------------------------------------------------------------------------
__global__ __launch_bounds__(256) void transpose_f32_bf16(
    const float* __restrict__ W, unsigned short* __restrict__ Wt, int K, int N)
{
    __shared__ unsigned short t[64][65];
    const int n0 = blockIdx.x * 64, k0 = blockIdx.y * 64;
    const int tid = threadIdx.x;
#pragma unroll
    for (int i = 0; i < 16; i++) {
        const int idx = tid + i * 256;
        const int r = idx >> 6, c = idx & 63;
        t[c][r] = f2bf(W[(long)(k0 + r) * N + (n0 + c)]);
    }
    __syncthreads();
#pragma unroll
    for (int i = 0; i < 16; i++) {
        const int idx = tid + i * 256;
        const int r = idx >> 6, c = idx & 63;
        Wt[(long)(n0 + r) * K + (k0 + c)] = t[r][c];
    }
}

// ---------------------------------------------------------------------------
// bf16 GEMM:  C[m][n] = sum_k A[m][k] * Bt[n][k]   (Bt = B^T layout)
// Tile 128x128, BK=32, 256 threads (4 waves, 64x64 each), mfma_f32_16x16x32_bf16.
// Staging: global_load_lds width=16, DOUBLE-buffered (round-6 A/B: dbuf 98us
// vs single-buf 110us on the fused scores dispatch — keep dbuf).
// XOR swizzle on the global k-chunk so MFMA-side ds_read_b128 is 2-way (free).
// SM: 0 bf16 row-major | 1 bf16 VhT head-split-transposed | 2 f32 row-major
//     3 scores-fused: P=exp(s*it) w/ mask; per-wave-parity partial row-sums ->
//       Lp[nb*2 + (wave&1)][z][row]  (16 exclusive slots: round-7 postmortem —
//       waves 0/1 share rows with different column halves; one slot per
//       column-half kills the store race without atomics)
//     4 PV: bf16 row-major scaled by 1/sum_{sl<16}(Lp[sl][z][row])
// ---------------------------------------------------------------------------
template <int SM>
__global__ __launch_bounds__(256) void gemm_bt(
    const unsigned short* __restrict__ A,
    const unsigned short* __restrict__ Bt,
    void* __restrict__ C,
    int K, int lda, int ldb, int ldc,
    long Ah, long Ab, long Bh, long Bb, long Ch, long Cb,
    int bg,
    const unsigned char* __restrict__ mask, float* __restrict__ L,
    float inv_temp, int b0)
{
    const int tid  = threadIdx.x;
    const int wave = tid >> 6;
    const int lane = tid & 63;
    const int quad = lane >> 4;
    const int l16  = lane & 15;

    const int z  = blockIdx.z;
    const int h  = z / bg;
    const int bi = z - h * bg;
    A  += h * Ah + (long)bi * Ab;
    Bt += h * Bh + (long)bi * Bb;

    const int m0 = blockIdx.y * 128;
    const int n0 = blockIdx.x * 128;

    __shared__ __align__(16) unsigned short As[2][128 * 32];
    __shared__ __align__(16) unsigned short Bs[2][128 * 32];
    __shared__ float Ls[128];  // PV: summed softmax denominators for this block's rows

    if (SM == 4) {
        // sum the 16 per-(n-block, wave-parity) partials once;
        // visible to all waves after the K-loop's first barrier
        if (tid < 128) {
            const float* Lz = L + ((long)z << 10) + m0 + tid;
            const long sls = (long)gridDim.z << 10;
            float s = 0.f;
#pragma unroll
            for (int sl = 0; sl < 16; sl++) s += Lz[sl * sls];
            Ls[tid] = s;
        }
    }

    f32x4 acc[4][4];
#pragma unroll
    for (int i = 0; i < 4; i++)
#pragma unroll
        for (int j = 0; j < 4; j++) acc[i][j] = (f32x4){0.f, 0.f, 0.f, 0.f};

    const int wr = (wave >> 1) * 64;
    const int wc = (wave & 1) * 64;

    // staging: pass p covers linear 16B-chunks idx = p*256 + tid
    // row = idx>>2, slot = idx&3, global kc = slot ^ ((row>>2)&3)
    const int r0 = tid >> 2;
    const int kc = (tid & 3) ^ ((r0 >> 2) & 3);

    const unsigned short* A0 = A + (long)(m0 + r0) * lda + kc * 8;
    const unsigned short* A1 = A + (long)(m0 + r0 + 64) * lda + kc * 8;
    const unsigned short* B0 = Bt + (long)(n0 + r0) * ldb + kc * 8;
    const unsigned short* B1 = Bt + (long)(n0 + r0 + 64) * ldb + kc * 8;

    auto stage = [&](int buf, int kt) {
        __builtin_amdgcn_global_load_lds((gbl_void_t*)(A0 + kt),
            (lds_void_t*)&As[buf][(wave * 64) * 8], 16, 0, 0);
        __builtin_amdgcn_global_load_lds((gbl_void_t*)(A1 + kt),
            (lds_void_t*)&As[buf][(256 + wave * 64) * 8], 16, 0, 0);
        __builtin_amdgcn_global_load_lds((gbl_void_t*)(B0 + kt),
            (lds_void_t*)&Bs[buf][(wave * 64) * 8], 16, 0, 0);
        __builtin_amdgcn_global_load_lds((gbl_void_t*)(B1 + kt),
            (lds_void_t*)&Bs[buf][(256 + wave * 64) * 8], 16, 0, 0);
    };

    const int sw = (l16 >> 2) & 3;  // read-side XOR swizzle

    stage(0, 0);
    int cur = 0;
    for (int kt = 0; kt < K; kt += 32) {
        __syncthreads();  // drains DMA(cur) issued a full compute phase ago
        if (kt + 32 < K) stage(cur ^ 1, kt + 32);

        bf16x8 af[4], bf[4];
#pragma unroll
        for (int mi = 0; mi < 4; mi++)
            af[mi] = *(const bf16x8*)&As[cur][(wr + mi * 16 + l16) * 32 + ((quad ^ sw) << 3)];
#pragma unroll
        for (int ni = 0; ni < 4; ni++)
            bf[ni] = *(const bf16x8*)&Bs[cur][(wc + ni * 16 + l16) * 32 + ((quad ^ sw) << 3)];

#pragma unroll
        for (int mi = 0; mi < 4; mi++)
#pragma unroll
            for (int ni = 0; ni < 4; ni++)
                acc[mi][ni] = __builtin_amdgcn_mfma_f32_16x16x32_bf16(
                    af[mi], bf[ni], acc[mi][ni], 0, 0, 0);
        cur ^= 1;
    }

    const long coff = h * Ch + (long)bi * Cb;
    if (SM == 0) {
        unsigned short* Cp = (unsigned short*)C + coff;
#pragma unroll
        for (int mi = 0; mi < 4; mi++)
#pragma unroll
            for (int ni = 0; ni < 4; ni++) {
                const int col = n0 + wc + ni * 16 + l16;
#pragma unroll
                for (int r = 0; r < 4; r++) {
                    const int row = m0 + wr + mi * 16 + quad * 4 + r;
                    Cp[(long)row * ldc + col] = f2bf(acc[mi][ni][r]);
                }
            }
    } else if (SM == 1) {
        // VhT store: col -> (h2=col>>9, d=col&511), row -> (bi2=row>>10, s=row&1023)
        unsigned short* Cp = (unsigned short*)C;
#pragma unroll
        for (int mi = 0; mi < 4; mi++)
#pragma unroll
            for (int ni = 0; ni < 4; ni++) {
                const int col = n0 + wc + ni * 16 + l16;
                const int h2 = col >> 9, d = col & 511;
                const int rowb = m0 + wr + mi * 16 + quad * 4;
                const int bi2 = rowb >> 10, s = rowb & 1023;
                us4 val = { f2bf(acc[mi][ni][0]), f2bf(acc[mi][ni][1]),
                            f2bf(acc[mi][ni][2]), f2bf(acc[mi][ni][3]) };
                *(us4*)&Cp[(((long)(h2 * bg + bi2) * 512 + d) << 10) + s] = val;
            }
    } else if (SM == 2) {
        float* Cp = (float*)C + coff;
#pragma unroll
        for (int mi = 0; mi < 4; mi++)
#pragma unroll
            for (int ni = 0; ni < 4; ni++) {
                const int col = n0 + wc + ni * 16 + l16;
#pragma unroll
                for (int r = 0; r < 4; r++) {
                    const int row = m0 + wr + mi * 16 + quad * 4 + r;
                    Cp[(long)row * ldc + col] = acc[mi][ni][r];
                }
            }
    } else if (SM == 3) {
        // fused scores epilogue: p = mask ? 0 : exp(s*inv_temp); store bf16;
        // 16-lane-reduced partial row-sums -> Lp[nb*2+(wave&1)][z][row]
        // (one exclusive slot per column-half; no atomics, no races).
        unsigned short* Cp = (unsigned short*)C + coff;
        const unsigned char* mb = mask + ((long)(b0 + bi) << 20);
        const int slot = blockIdx.x * 2 + (wave & 1);
        float* Lz = L + ((long)(slot * gridDim.z + z) << 10);
#pragma unroll
        for (int mi = 0; mi < 4; mi++) {
#pragma unroll
            for (int r = 0; r < 4; r++) {
                const int row = m0 + wr + mi * 16 + quad * 4 + r;
                float rs = 0.f;
#pragma unroll
                for (int ni = 0; ni < 4; ni++) {
                    const int col = n0 + wc + ni * 16 + l16;
                    float p = __expf(acc[mi][ni][r] * inv_temp);
                    if (mb[((long)row << 10) + col] != 0) p = 0.f;
                    Cp[(long)row * ldc + col] = f2bf(p);
                    rs += p;
                }
#pragma unroll
                for (int m = 1; m < 16; m <<= 1) rs += __shfl_xor(rs, m);
                if (l16 == 0) Lz[row] = rs;
            }
        }
    } else {
        // PV epilogue: scale by 1/Ls[row-m0] (LDS broadcast), bf16 row-major store.
        unsigned short* Cp = (unsigned short*)C + coff;
#pragma unroll
        for (int mi = 0; mi < 4; mi++)
#pragma unroll
            for (int r = 0; r < 4; r++) {
                const int row = m0 + wr + mi * 16 + quad * 4 + r;
                const float inv = 1.0f / Ls[row - m0];
#pragma unroll
                for (int ni = 0; ni < 4; ni++) {
                    const int col = n0 + wc + ni * 16 + l16;
                    Cp[(long)row * ldc + col] = f2bf(acc[mi][ni][r] * inv);
                }
            }
    }
}

// ---------------------------------------------------------------------------
// Fused: sum 4 split-K partials (f32, rows of 512) + LayerNorm -> f32 out.
// ---------------------------------------------------------------------------
__global__ __launch_bounds__(256) void ln_rows_red4(
    const float* __restrict__ Yp, long zs,
    const float* __restrict__ gamma,
    const float* __restrict__ beta,
    float* __restrict__ out)
{
    __shared__ float red[4];
    const long row = blockIdx.x;
    const float* y = Yp + (row << 9);
    const int tid = threadIdx.x;
    const int wave = tid >> 6, lane = tid & 63;

    float v0 = y[tid] + y[zs + tid] + y[2 * zs + tid] + y[3 * zs + tid];
    float v1 = y[tid + 256] + y[zs + tid + 256] + y[2 * zs + tid + 256] + y[3 * zs + tid + 256];
    float sm = v0 + v1;
#pragma unroll
    for (int i = 32; i > 0; i >>= 1) sm += __shfl_xor(sm, i);
    if (lane == 0) red[wave] = sm;
    __syncthreads();
    sm = red[0] + red[1] + red[2] + red[3];
    __syncthreads();
    const float mu = sm * (1.0f / 512.0f);

    const float d0 = v0 - mu, d1 = v1 - mu;
    float sq = d0 * d0 + d1 * d1;
#pragma unroll
    for (int i = 32; i > 0; i >>= 1) sq += __shfl_xor(sq, i);
    if (lane == 0) red[wave] = sq;
    __syncthreads();
    sq = red[0] + red[1] + red[2] + red[3];
    const float inv = rsqrtf(sq * (1.0f / 512.0f) + 1e-5f);

    out[(row << 9) + tid]       = d0 * inv * gamma[tid]       + beta[tid];
    out[(row << 9) + tid + 256] = d1 * inv * gamma[tid + 256] + beta[tid + 256];
}

// ---------------------------------------------------------------------------
extern "C" void kernel_launch(void* const* d_in, const int* in_sizes, int n_in,
                              void* d_out, int out_size, void* d_ws, size_t ws_size,
                              hipStream_t stream)
{
    const float* q_f  = (const float*)d_in[0];
    const float* k_f  = (const float*)d_in[1];
    const float* v_f  = (const float*)d_in[2];
    const float* Wq_f = (const float*)d_in[3];
    const float* Wk_f = (const float*)d_in[4];
    const float* Wv_f = (const float*)d_in[5];
    const float* Wo_f = (const float*)d_in[6];
    const float* ga_f = (const float*)d_in[7];
    const float* be_f = (const float*)d_in[8];
    const unsigned char* mask = (const unsigned char*)d_in[9];
    float* out = (float*)d_out;

    constexpr int B = 8, S = 1024, DM = 512, H = 8, DH = 512, HD = H * DH;  // HD=4096
    const float inv_temp = 0.044194173824159216f;  // 1/sqrt(512)

    size_t off = 0;
    auto alloc = [&](size_t bytes) {
        void* p = (char*)d_ws + off;
        off += (bytes + 255) & ~(size_t)255;
        return p;
    };
    unsigned short* qb  = (unsigned short*)alloc((size_t)B * S * DM * 2);
    unsigned short* kb  = (unsigned short*)alloc((size_t)B * S * DM * 2);
    unsigned short* vb  = (unsigned short*)alloc((size_t)B * S * DM * 2);
    unsigned short* WqT = (unsigned short*)alloc((size_t)HD * DM * 2);
    unsigned short* WkT = (unsigned short*)alloc((size_t)HD * DM * 2);
    unsigned short* WvT = (unsigned short*)alloc((size_t)HD * DM * 2);
    unsigned short* WoT = (unsigned short*)alloc((size_t)DH * HD * 2);
    const size_t fixed = off;

    // Ypart (4 split-K f32 partials) aliases P (dead after PV).
    const size_t perbatch = (size_t)4 * S * HD * 2   // Qh,Kh,VhT,AO
                          + (size_t)H * S * S * 2    // P / Ypart
                          + (size_t)16 * H * S * 4   // Lp (16 partial slots)
                          + 8 * 256;
    int bg = 8;
    while (bg > 1 && fixed + perbatch * (size_t)bg > ws_size) bg >>= 1;

    unsigned short* Qh  = (unsigned short*)alloc((size_t)bg * S * HD * 2);
    unsigned short* Kh  = (unsigned short*)alloc((size_t)bg * S * HD * 2);
    unsigned short* VhT = (unsigned short*)alloc((size_t)bg * S * HD * 2);
    unsigned short* AO  = (unsigned short*)alloc((size_t)bg * S * HD * 2);
    float* Lp = (float*)alloc((size_t)16 * H * bg * S * 4);
    void* PY = alloc((size_t)H * bg * S * S * 2);  // >= 4*bg*S*DH*4
    unsigned short* P = (unsigned short*)PY;
    float* Ypart = (float*)PY;

    // ---- canonicalization: f32 -> bf16 (+ weight transposes) ----
    const long nqkv4 = (long)B * S * DM / 4;
    conv_f32_bf16<<<2048, 256, 0, stream>>>(q_f, qb, nqkv4);
    conv_f32_bf16<<<2048, 256, 0, stream>>>(k_f, kb, nqkv4);
    conv_f32_bf16<<<2048, 256, 0, stream>>>(v_f, vb, nqkv4);
    transpose_f32_bf16<<<dim3(HD / 64, DM / 64), 256, 0, stream>>>(Wq_f, WqT, DM, HD);
    transpose_f32_bf16<<<dim3(HD / 64, DM / 64), 256, 0, stream>>>(Wk_f, WkT, DM, HD);
    transpose_f32_bf16<<<dim3(HD / 64, DM / 64), 256, 0, stream>>>(Wv_f, WvT, DM, HD);
    transpose_f32_bf16<<<dim3(DH / 64, HD / 64), 256, 0, stream>>>(Wo_f, WoT, HD, DH);

    for (int g = 0; g < B / bg; g++) {
        const long inoff = (long)g * bg * S * DM;
        const int  Mg = bg * S;

        // ---- QKV projections: (Mg x 512) x (512 x 4096) ----
        gemm_bt<0><<<dim3(HD / 128, Mg / 128, 1), 256, 0, stream>>>(
            qb + inoff, WqT, Qh, DM, DM, DM, HD, 0, 0, 0, 0, 0, 0, bg,
            nullptr, nullptr, 0.f, 0);
        gemm_bt<0><<<dim3(HD / 128, Mg / 128, 1), 256, 0, stream>>>(
            kb + inoff, WkT, Kh, DM, DM, DM, HD, 0, 0, 0, 0, 0, 0, bg,
            nullptr, nullptr, 0.f, 0);
        gemm_bt<1><<<dim3(HD / 128, Mg / 128, 1), 256, 0, stream>>>(
            vb + inoff, WvT, VhT, DM, DM, DM, HD, 0, 0, 0, 0, 0, 0, bg,
            nullptr, nullptr, 0.f, 0);

        // ---- fused scores+exp+mask: P = exp(QK^T*it), Lp = partial row-sums ----
        gemm_bt<3><<<dim3(S / 128, S / 128, H * bg), 256, 0, stream>>>(
            Qh, Kh, P, DH, HD, HD, S,
            (long)DH, (long)S * HD,
            (long)DH, (long)S * HD,
            (long)bg * S * S, (long)S * S,
            bg, mask, Lp, inv_temp, g * bg);

        // ---- PV with 1/L normalization: AO = (P/L) * V ----
        gemm_bt<4><<<dim3(DH / 128, S / 128, H * bg), 256, 0, stream>>>(
            P, VhT, AO, S, S, S, HD,
            (long)bg * S * S, (long)S * S,
            (long)bg * DH * S, (long)DH * S,
            (long)DH, (long)S * HD,
            bg, nullptr, Lp, 0.f, 0);

        // ---- O-projection, split-K x4 -> Ypart ----
        gemm_bt<2><<<dim3(DH / 128, Mg / 128, 4), 256, 0, stream>>>(
            AO, WoT, Ypart, HD / 4, HD, HD, DH,
            1024, 0, 1024, 0, (long)Mg * DH, 0, 1,
            nullptr, nullptr, 0.f, 0);

        // ---- reduce partials + LayerNorm -> f32 out ----
        ln_rows_red4<<<dim3(Mg), 256, 0, stream>>>(
            Ypart, (long)Mg * DH, ga_f, be_f, out + (long)g * bg * S * DH);
    }
}

// Round 9
// 675.393 us; speedup vs baseline: 1.1442x; 1.0809x over previous
//
#include <hip/hip_runtime.h>

typedef __attribute__((ext_vector_type(8))) short bf16x8;
typedef __attribute__((ext_vector_type(4))) float f32x4;
typedef __attribute__((ext_vector_type(4))) unsigned short us4;

typedef __attribute__((address_space(3))) void lds_void_t;
typedef const __attribute__((address_space(1))) void gbl_void_t;

__device__ __forceinline__ float bf2f(unsigned short u) {
    union { unsigned int i; float f; } x; x.i = ((unsigned int)u) << 16; return x.f;
}
__device__ __forceinline__ unsigned short f2bf(float f) {
    union { float f; unsigned int i; } x; x.f = f;
    unsigned int u = x.i;
    unsigned int r = (u + 0x7FFFu + ((u >> 16) & 1u)) >> 16;  // RNE
    return (unsigned short)r;
}

// ---------------------------------------------------------------------------
// f32 -> bf16 convert, 4 elems/thread, grid-stride.
// ---------------------------------------------------------------------------
__global__ __launch_bounds__(256) void conv_f32_bf16(
    const float* __restrict__ src, unsigned short* __restrict__ dst, long n4)
{
    long i = (long)blockIdx.x * blockDim.x + threadIdx.x;
    const long stride = (long)gridDim.x * blockDim.x;
    const float4* s = (const float4*)src;
    for (; i < n4; i += stride) {
        float4 v = s[i];
        us4 o = { f2bf(v.x), f2bf(v.y), f2bf(v.z), f2bf(v.w) };
        *(us4*)&dst[i * 4] = o;
    }
}

// ---------------------------------------------------------------------------
// Transpose: W(K x N) f32 -> Wt(N x K) bf16. 64x64 LDS tiles.
// ---------------------------------------------------------------------------
__global__ __launch_bounds__(256) void transpose_f32_bf16(
    const float* __restrict__ W, unsigned short* __restrict__ Wt, int K, int N)
{
    __shared__ unsigned short t[64][65];
    const int n0 = blockIdx.x * 64, k0 = blockIdx.y * 64;
    const int tid = threadIdx.x;
#pragma unroll
    for (int i = 0; i < 16; i++) {
        const int idx = tid + i * 256;
        const int r = idx >> 6, c = idx & 63;
        t[c][r] = f2bf(W[(long)(k0 + r) * N + (n0 + c)]);
    }
    __syncthreads();
#pragma unroll
    for (int i = 0; i < 16; i++) {
        const int idx = tid + i * 256;
        const int r = idx >> 6, c = idx & 63;
        Wt[(long)(n0 + r) * K + (k0 + c)] = t[r][c];
    }
}

// ---------------------------------------------------------------------------
// bf16 GEMM:  C[m][n] = sum_k A[m][k] * Bt[n][k]   (Bt = B^T layout)
// Tile 128x128, BK=32, 256 threads (4 waves, 64x64 each), mfma_f32_16x16x32_bf16.
// Staging: global_load_lds width=16, DOUBLE-buffered (measured: dbuf 98us vs
// single-buf 110us, round 6). XOR swizzle -> ds_read_b128 is 2-way (free).
// SWZ (XCD-aware block swizzle; XCD == blockIdx.x when gridDim.x==8 [dispatch
// index % 8], so blockIdx.x selects a z-subset => per-XCD L2 keeps one z's
// tiles resident; round-8 evidence: scores FETCH 186MB vs 64MB ideal):
//   0: z=bz, m0=by, n0=bx (plain)
//   1: z=bx*(Z/8)+bz/8, n0=(bz&7), m0=by      (scores: 8 n-blocks)
//   2: z=bx*(Z/8)+bz/8, m0=(bz&7), n0=by      (PV: 8 m-blocks)
// SM: 0 bf16 row-major | 1 bf16 VhT head-split-transposed | 2 f32 row-major
//     3 scores-fused: P=exp(s*it) w/ mask; partial row-sums ->
//       Lp[nb*2+(wave&1)][z][row] (16 exclusive slots, no atomics)
//     4 PV: bf16 row-major scaled by 1/sum_{sl<16}(Lp[sl][z][row])
// ---------------------------------------------------------------------------
template <int SM, int SWZ>
__global__ __launch_bounds__(256) void gemm_bt(
    const unsigned short* __restrict__ A,
    const unsigned short* __restrict__ Bt,
    void* __restrict__ C,
    int K, int lda, int ldb, int ldc,
    long Ah, long Ab, long Bh, long Bb, long Ch, long Cb,
    int bg,
    const unsigned char* __restrict__ mask, float* __restrict__ L,
    float inv_temp, int b0)
{
    const int tid  = threadIdx.x;
    const int wave = tid >> 6;
    const int lane = tid & 63;
    const int quad = lane >> 4;
    const int l16  = lane & 15;

    int z, m0, n0;
    if (SWZ == 0) {
        z = blockIdx.z; m0 = blockIdx.y << 7; n0 = blockIdx.x << 7;
    } else {
        z = blockIdx.x * (gridDim.z >> 3) + (blockIdx.z >> 3);
        if (SWZ == 1) { n0 = (blockIdx.z & 7) << 7; m0 = blockIdx.y << 7; }
        else          { m0 = (blockIdx.z & 7) << 7; n0 = blockIdx.y << 7; }
    }
    const int h  = z / bg;
    const int bi = z - h * bg;
    A  += h * Ah + (long)bi * Ab;
    Bt += h * Bh + (long)bi * Bb;

    __shared__ __align__(16) unsigned short As[2][128 * 32];
    __shared__ __align__(16) unsigned short Bs[2][128 * 32];
    __shared__ float Ls[128];  // PV: summed softmax denominators

    if (SM == 4) {
        // sum the 16 partial slots once; visible after the K-loop's 1st barrier
        if (tid < 128) {
            const float* Lz = L + ((long)z << 10) + m0 + tid;
            const long sls = (long)gridDim.z << 10;
            float s = 0.f;
#pragma unroll
            for (int sl = 0; sl < 16; sl++) s += Lz[sl * sls];
            Ls[tid] = s;
        }
    }

    f32x4 acc[4][4];
#pragma unroll
    for (int i = 0; i < 4; i++)
#pragma unroll
        for (int j = 0; j < 4; j++) acc[i][j] = (f32x4){0.f, 0.f, 0.f, 0.f};

    const int wr = (wave >> 1) * 64;
    const int wc = (wave & 1) * 64;

    const int r0 = tid >> 2;
    const int kc = (tid & 3) ^ ((r0 >> 2) & 3);

    const unsigned short* A0 = A + (long)(m0 + r0) * lda + kc * 8;
    const unsigned short* A1 = A + (long)(m0 + r0 + 64) * lda + kc * 8;
    const unsigned short* B0 = Bt + (long)(n0 + r0) * ldb + kc * 8;
    const unsigned short* B1 = Bt + (long)(n0 + r0 + 64) * ldb + kc * 8;

    auto stage = [&](int buf, int kt) {
        __builtin_amdgcn_global_load_lds((gbl_void_t*)(A0 + kt),
            (lds_void_t*)&As[buf][(wave * 64) * 8], 16, 0, 0);
        __builtin_amdgcn_global_load_lds((gbl_void_t*)(A1 + kt),
            (lds_void_t*)&As[buf][(256 + wave * 64) * 8], 16, 0, 0);
        __builtin_amdgcn_global_load_lds((gbl_void_t*)(B0 + kt),
            (lds_void_t*)&Bs[buf][(wave * 64) * 8], 16, 0, 0);
        __builtin_amdgcn_global_load_lds((gbl_void_t*)(B1 + kt),
            (lds_void_t*)&Bs[buf][(256 + wave * 64) * 8], 16, 0, 0);
    };

    const int sw = (l16 >> 2) & 3;  // read-side XOR swizzle

    stage(0, 0);
    int cur = 0;
    for (int kt = 0; kt < K; kt += 32) {
        __syncthreads();  // drains DMA(cur) issued a full compute phase ago
        if (kt + 32 < K) stage(cur ^ 1, kt + 32);

        bf16x8 af[4], bf[4];
#pragma unroll
        for (int mi = 0; mi < 4; mi++)
            af[mi] = *(const bf16x8*)&As[cur][(wr + mi * 16 + l16) * 32 + ((quad ^ sw) << 3)];
#pragma unroll
        for (int ni = 0; ni < 4; ni++)
            bf[ni] = *(const bf16x8*)&Bs[cur][(wc + ni * 16 + l16) * 32 + ((quad ^ sw) << 3)];

#pragma unroll
        for (int mi = 0; mi < 4; mi++)
#pragma unroll
            for (int ni = 0; ni < 4; ni++)
                acc[mi][ni] = __builtin_amdgcn_mfma_f32_16x16x32_bf16(
                    af[mi], bf[ni], acc[mi][ni], 0, 0, 0);
        cur ^= 1;
    }

    const long coff = h * Ch + (long)bi * Cb;
    if (SM == 0) {
        unsigned short* Cp = (unsigned short*)C + coff;
#pragma unroll
        for (int mi = 0; mi < 4; mi++)
#pragma unroll
            for (int ni = 0; ni < 4; ni++) {
                const int col = n0 + wc + ni * 16 + l16;
#pragma unroll
                for (int r = 0; r < 4; r++) {
                    const int row = m0 + wr + mi * 16 + quad * 4 + r;
                    Cp[(long)row * ldc + col] = f2bf(acc[mi][ni][r]);
                }
            }
    } else if (SM == 1) {
        // VhT store: col -> (h2=col>>9, d=col&511), row -> (bi2=row>>10, s=row&1023)
        unsigned short* Cp = (unsigned short*)C;
#pragma unroll
        for (int mi = 0; mi < 4; mi++)
#pragma unroll
            for (int ni = 0; ni < 4; ni++) {
                const int col = n0 + wc + ni * 16 + l16;
                const int h2 = col >> 9, d = col & 511;
                const int rowb = m0 + wr + mi * 16 + quad * 4;
                const int bi2 = rowb >> 10, s = rowb & 1023;
                us4 val = { f2bf(acc[mi][ni][0]), f2bf(acc[mi][ni][1]),
                            f2bf(acc[mi][ni][2]), f2bf(acc[mi][ni][3]) };
                *(us4*)&Cp[(((long)(h2 * bg + bi2) * 512 + d) << 10) + s] = val;
            }
    } else if (SM == 2) {
        float* Cp = (float*)C + coff;
#pragma unroll
        for (int mi = 0; mi < 4; mi++)
#pragma unroll
            for (int ni = 0; ni < 4; ni++) {
                const int col = n0 + wc + ni * 16 + l16;
#pragma unroll
                for (int r = 0; r < 4; r++) {
                    const int row = m0 + wr + mi * 16 + quad * 4 + r;
                    Cp[(long)row * ldc + col] = acc[mi][ni][r];
                }
            }
    } else if (SM == 3) {
        // fused scores epilogue: p = mask ? 0 : exp(s*inv_temp); store bf16;
        // 16-lane-reduced partial row-sums -> Lp[nb*2+(wave&1)][z][row]
        unsigned short* Cp = (unsigned short*)C + coff;
        const unsigned char* mb = mask + ((long)(b0 + bi) << 20);
        const int slot = (n0 >> 7) * 2 + (wave & 1);
        float* Lz = L + ((long)(slot * gridDim.z + z) << 10);
#pragma unroll
        for (int mi = 0; mi < 4; mi++) {
#pragma unroll
            for (int r = 0; r < 4; r++) {
                const int row = m0 + wr + mi * 16 + quad * 4 + r;
                float rs = 0.f;
#pragma unroll
                for (int ni = 0; ni < 4; ni++) {
                    const int col = n0 + wc + ni * 16 + l16;
                    float p = __expf(acc[mi][ni][r] * inv_temp);
                    if (mb[((long)row << 10) + col] != 0) p = 0.f;
                    Cp[(long)row * ldc + col] = f2bf(p);
                    rs += p;
                }
#pragma unroll
                for (int m = 1; m < 16; m <<= 1) rs += __shfl_xor(rs, m);
                if (l16 == 0) Lz[row] = rs;
            }
        }
    } else {
        // PV epilogue: scale by 1/Ls[row-m0] (LDS broadcast), bf16 row-major store.
        unsigned short* Cp = (unsigned short*)C + coff;
#pragma unroll
        for (int mi = 0; mi < 4; mi++)
#pragma unroll
            for (int r = 0; r < 4; r++) {
                const int row = m0 + wr + mi * 16 + quad * 4 + r;
                const float inv = 1.0f / Ls[row - m0];
#pragma unroll
                for (int ni = 0; ni < 4; ni++) {
                    const int col = n0 + wc + ni * 16 + l16;
                    Cp[(long)row * ldc + col] = f2bf(acc[mi][ni][r] * inv);
                }
            }
    }
}

// ---------------------------------------------------------------------------
// Fused: sum 4 split-K partials (f32, rows of 512) + LayerNorm -> f32 out.
// ---------------------------------------------------------------------------
__global__ __launch_bounds__(256) void ln_rows_red4(
    const float* __restrict__ Yp, long zs,
    const float* __restrict__ gamma,
    const float* __restrict__ beta,
    float* __restrict__ out)
{
    __shared__ float red[4];
    const long row = blockIdx.x;
    const float* y = Yp + (row << 9);
    const int tid = threadIdx.x;
    const int wave = tid >> 6, lane = tid & 63;

    float v0 = y[tid] + y[zs + tid] + y[2 * zs + tid] + y[3 * zs + tid];
    float v1 = y[tid + 256] + y[zs + tid + 256] + y[2 * zs + tid + 256] + y[3 * zs + tid + 256];
    float sm = v0 + v1;
#pragma unroll
    for (int i = 32; i > 0; i >>= 1) sm += __shfl_xor(sm, i);
    if (lane == 0) red[wave] = sm;
    __syncthreads();
    sm = red[0] + red[1] + red[2] + red[3];
    __syncthreads();
    const float mu = sm * (1.0f / 512.0f);

    const float d0 = v0 - mu, d1 = v1 - mu;
    float sq = d0 * d0 + d1 * d1;
#pragma unroll
    for (int i = 32; i > 0; i >>= 1) sq += __shfl_xor(sq, i);
    if (lane == 0) red[wave] = sq;
    __syncthreads();
    sq = red[0] + red[1] + red[2] + red[3];
    const float inv = rsqrtf(sq * (1.0f / 512.0f) + 1e-5f);

    out[(row << 9) + tid]       = d0 * inv * gamma[tid]       + beta[tid];
    out[(row << 9) + tid + 256] = d1 * inv * gamma[tid + 256] + beta[tid + 256];
}

// ---------------------------------------------------------------------------
extern "C" void kernel_launch(void* const* d_in, const int* in_sizes, int n_in,
                              void* d_out, int out_size, void* d_ws, size_t ws_size,
                              hipStream_t stream)
{
    const float* q_f  = (const float*)d_in[0];
    const float* k_f  = (const float*)d_in[1];
    const float* v_f  = (const float*)d_in[2];
    const float* Wq_f = (const float*)d_in[3];
    const float* Wk_f = (const float*)d_in[4];
    const float* Wv_f = (const float*)d_in[5];
    const float* Wo_f = (const float*)d_in[6];
    const float* ga_f = (const float*)d_in[7];
    const float* be_f = (const float*)d_in[8];
    const unsigned char* mask = (const unsigned char*)d_in[9];
    float* out = (float*)d_out;

    constexpr int B = 8, S = 1024, DM = 512, H = 8, DH = 512, HD = H * DH;  // HD=4096
    const float inv_temp = 0.044194173824159216f;  // 1/sqrt(512)

    size_t off = 0;
    auto alloc = [&](size_t bytes) {
        void* p = (char*)d_ws + off;
        off += (bytes + 255) & ~(size_t)255;
        return p;
    };
    unsigned short* qb  = (unsigned short*)alloc((size_t)B * S * DM * 2);
    unsigned short* kb  = (unsigned short*)alloc((size_t)B * S * DM * 2);
    unsigned short* vb  = (unsigned short*)alloc((size_t)B * S * DM * 2);
    unsigned short* WqT = (unsigned short*)alloc((size_t)HD * DM * 2);
    unsigned short* WkT = (unsigned short*)alloc((size_t)HD * DM * 2);
    unsigned short* WvT = (unsigned short*)alloc((size_t)HD * DM * 2);
    unsigned short* WoT = (unsigned short*)alloc((size_t)DH * HD * 2);
    const size_t fixed = off;

    // AO aliases Qh (dead after scores); Ypart aliases P (dead after PV).
    const size_t perbatch = (size_t)3 * S * HD * 2   // Qh(/AO), Kh, VhT
                          + (size_t)H * S * S * 2    // P / Ypart
                          + (size_t)16 * H * S * 4   // Lp (16 partial slots)
                          + 8 * 256;
    int bg = 8;
    while (bg > 1 && fixed + perbatch * (size_t)bg > ws_size) bg >>= 1;

    unsigned short* Qh  = (unsigned short*)alloc((size_t)bg * S * HD * 2);
    unsigned short* Kh  = (unsigned short*)alloc((size_t)bg * S * HD * 2);
    unsigned short* VhT = (unsigned short*)alloc((size_t)bg * S * HD * 2);
    unsigned short* AO  = Qh;  // alias: Qh dead once scores completes
    float* Lp = (float*)alloc((size_t)16 * H * bg * S * 4);
    void* PY = alloc((size_t)H * bg * S * S * 2);  // >= 4*bg*S*DH*4
    unsigned short* P = (unsigned short*)PY;
    float* Ypart = (float*)PY;

    // ---- canonicalization: f32 -> bf16 (+ weight transposes) ----
    const long nqkv4 = (long)B * S * DM / 4;
    conv_f32_bf16<<<2048, 256, 0, stream>>>(q_f, qb, nqkv4);
    conv_f32_bf16<<<2048, 256, 0, stream>>>(k_f, kb, nqkv4);
    conv_f32_bf16<<<2048, 256, 0, stream>>>(v_f, vb, nqkv4);
    transpose_f32_bf16<<<dim3(HD / 64, DM / 64), 256, 0, stream>>>(Wq_f, WqT, DM, HD);
    transpose_f32_bf16<<<dim3(HD / 64, DM / 64), 256, 0, stream>>>(Wk_f, WkT, DM, HD);
    transpose_f32_bf16<<<dim3(HD / 64, DM / 64), 256, 0, stream>>>(Wv_f, WvT, DM, HD);
    transpose_f32_bf16<<<dim3(DH / 64, HD / 64), 256, 0, stream>>>(Wo_f, WoT, HD, DH);

    for (int g = 0; g < B / bg; g++) {
        const long inoff = (long)g * bg * S * DM;
        const int  Mg = bg * S;
        const int  Z  = H * bg;

        // ---- QKV projections: (Mg x 512) x (512 x 4096) ----
        gemm_bt<0, 0><<<dim3(HD / 128, Mg / 128, 1), 256, 0, stream>>>(
            qb + inoff, WqT, Qh, DM, DM, DM, HD, 0, 0, 0, 0, 0, 0, bg,
            nullptr, nullptr, 0.f, 0);
        gemm_bt<0, 0><<<dim3(HD / 128, Mg / 128, 1), 256, 0, stream>>>(
            kb + inoff, WkT, Kh, DM, DM, DM, HD, 0, 0, 0, 0, 0, 0, bg,
            nullptr, nullptr, 0.f, 0);
        gemm_bt<1, 0><<<dim3(HD / 128, Mg / 128, 1), 256, 0, stream>>>(
            vb + inoff, WvT, VhT, DM, DM, DM, HD, 0, 0, 0, 0, 0, 0, bg,
            nullptr, nullptr, 0.f, 0);

        // ---- fused scores+exp+mask, XCD-swizzled (bx = z-subset, bz = n|zlow) ----
        gemm_bt<3, 1><<<dim3(8, 8, Z), 256, 0, stream>>>(
            Qh, Kh, P, DH, HD, HD, S,
            (long)DH, (long)S * HD,
            (long)DH, (long)S * HD,
            (long)bg * S * S, (long)S * S,
            bg, mask, Lp, inv_temp, g * bg);

        // ---- PV with 1/L normalization, XCD-swizzled (bz = m|zlow) ----
        gemm_bt<4, 2><<<dim3(8, 4, Z), 256, 0, stream>>>(
            P, VhT, AO, S, S, S, HD,
            (long)bg * S * S, (long)S * S,
            (long)bg * DH * S, (long)DH * S,
            (long)DH, (long)S * HD,
            bg, nullptr, Lp, 0.f, 0);

        // ---- O-projection, split-K x4 -> Ypart ----
        gemm_bt<2, 0><<<dim3(DH / 128, Mg / 128, 4), 256, 0, stream>>>(
            AO, WoT, Ypart, HD / 4, HD, HD, DH,
            1024, 0, 1024, 0, (long)Mg * DH, 0, 1,
            nullptr, nullptr, 0.f, 0);

        // ---- reduce partials + LayerNorm -> f32 out ----
        ln_rows_red4<<<dim3(Mg), 256, 0, stream>>>(
            Ypart, (long)Mg * DH, ga_f, be_f, out + (long)g * bg * S * DH);
    }
}